// Round 2
// baseline (384.824 us; speedup 1.0000x reference)
//
#include <hip/hip_runtime.h>
#include <math.h>

#define WAVE 64

// Native clang vector type — required for __builtin_nontemporal_load.
typedef float nfloat4 __attribute__((ext_vector_type(4)));

// Shapes fixed by reference: B=64, T=2048, Q=512, K=512.

// ---------------------------------------------------------------------------
// Fast out = exp(tanh(u)).
// tanh(u) = 1 - 2/(1 + e^{2u}); e^{2u} via v_exp_f32 (exp2), 2/(1+z) via
// v_rcp_f32. Saturates correctly: u>>0 -> z=inf -> rcp=0 -> t=1;
// u<<0 -> z=0 -> t=-1. ~8 VALU instrs vs ~100 for libm tanhf+expf.
// ---------------------------------------------------------------------------
#define LOG2E 1.44269504088896f
__device__ __forceinline__ float exp_tanh(float u) {
    float z = __builtin_amdgcn_exp2f(2.0f * LOG2E * u);   // e^{2u}
    float t = 1.0f - 2.0f * __builtin_amdgcn_rcpf(1.0f + z);
    return __builtin_amdgcn_exp2f(LOG2E * t);
}

// ---------------------------------------------------------------------------
// Reduce-scatter + broadcast: input s[0..7] = per-lane partials of 8 rows.
// Output: every lane holds the FULL 64-lane sum of row r = (lane>>3)&7.
// 10 shuffles total vs 48 for the naive 6-step-butterfly-per-row.
// ---------------------------------------------------------------------------
__device__ __forceinline__ float reduce8(const float s[8]) {
    const int lane = (int)(threadIdx.x & 63);
    const bool hi32 = (lane & 32) != 0;
    float v[4];
    #pragma unroll
    for (int r = 0; r < 4; ++r) {
        float keep = hi32 ? s[r + 4] : s[r];
        float send = hi32 ? s[r] : s[r + 4];
        v[r] = keep + __shfl_xor(send, 32, WAVE);
    }
    const bool hi16 = (lane & 16) != 0;
    float w[2];
    #pragma unroll
    for (int r = 0; r < 2; ++r) {
        float keep = hi16 ? v[r + 2] : v[r];
        float send = hi16 ? v[r] : v[r + 2];
        w[r] = keep + __shfl_xor(send, 16, WAVE);
    }
    const bool hi8 = (lane & 8) != 0;
    float keep = hi8 ? w[1] : w[0];
    float send = hi8 ? w[0] : w[1];
    float x = keep + __shfl_xor(send, 8, WAVE);
    x += __shfl_xor(x, 4, WAVE);
    x += __shfl_xor(x, 2, WAVE);
    x += __shfl_xor(x, 1, WAVE);
    return x;
}

// ---------------------------------------------------------------------------
// Kernel 1: mids[b,k] = sum_q W[k,q] * query[b,q]
// One wave per 8 consecutive k for one b. W (1 MB) is L2/L3-resident.
// Also zeroes the 64 softmax denominators (stream-ordered before scores).
// ---------------------------------------------------------------------------
__global__ __launch_bounds__(256, 4)
void mids_kernel(const float* __restrict__ W,
                 const float* __restrict__ query,
                 float* __restrict__ mids,
                 float* __restrict__ sums) {
    if (blockIdx.x == 0 && threadIdx.x < 64) sums[threadIdx.x] = 0.f;

    const int gwave = (int)((blockIdx.x * blockDim.x + threadIdx.x) >> 6);
    const int lane  = threadIdx.x & 63;
    const int b  = gwave >> 6;          // 64 waves per batch row (512/8)
    const int k0 = (gwave & 63) * 8;

    const float4* qrow = (const float4*)(query + (size_t)b * 512);
    const float4 q0 = qrow[lane];
    const float4 q1 = qrow[lane + 64];

    float s[8];
    #pragma unroll
    for (int r = 0; r < 8; ++r) {
        const float4* wrow = (const float4*)(W + (size_t)(k0 + r) * 512);
        float4 a = wrow[lane];
        float4 c = wrow[lane + 64];
        s[r] = a.x*q0.x + a.y*q0.y + a.z*q0.z + a.w*q0.w
             + c.x*q1.x + c.y*q1.y + c.z*q1.z + c.w*q1.w;
    }
    float x = reduce8(s);
    // Lanes 0,8,...,56 hold rows 0..7 -> 8 consecutive dwords, coalesced.
    if ((lane & 7) == 0)
        mids[(size_t)gwave * 8 + ((lane >> 3) & 7)] = x;
}

// ---------------------------------------------------------------------------
// Kernel 2: out[b,t] = exp(tanh(key[b,t,:].mids[b,:] + bias)) (unnormalized)
// tanh in (-1,1) => exp cannot overflow => max-subtraction unnecessary, so
// the softmax numerator fuses here; per-wave exp-sum -> atomicAdd sums[b].
// 16 rows per wave, two 8-row groups, 16 NT float4 loads in flight/group.
// __launch_bounds__(256,4) pins >=4 waves/SIMD (VGPR<=128) so the 268 MB
// stream stays BW-bound, not latency-bound.
// ---------------------------------------------------------------------------
__global__ __launch_bounds__(256, 4)
void scores_kernel(const float* __restrict__ key,
                   const float* __restrict__ mids,
                   const float* __restrict__ bias,
                   float* __restrict__ out,
                   float* __restrict__ sums) {
    const int gwave = (int)((blockIdx.x * blockDim.x + threadIdx.x) >> 6);
    const int lane  = threadIdx.x & 63;
    const int row0  = gwave * 16;          // flattened (b*T + t)
    const int b     = row0 >> 11;          // T = 2048

    const float4* mrow = (const float4*)(mids + (size_t)b * 512);
    const float4 m0 = mrow[lane];
    const float4 m1 = mrow[lane + 64];
    const float bv = bias[0];

    const nfloat4* kbase = (const nfloat4*)key + (size_t)row0 * 128;  // 128 f4/row

    float wave_sum = 0.f;

    #pragma unroll
    for (int g = 0; g < 2; ++g) {          // two 8-row groups
        const int r0 = g * 8;
        nfloat4 a[8], c[8];
        #pragma unroll
        for (int r = 0; r < 8; ++r) {
            a[r] = __builtin_nontemporal_load(&kbase[(size_t)(r0 + r) * 128 + lane]);
            c[r] = __builtin_nontemporal_load(&kbase[(size_t)(r0 + r) * 128 + lane + 64]);
        }
        float s[8];
        #pragma unroll
        for (int r = 0; r < 8; ++r) {
            s[r] = a[r].x*m0.x + a[r].y*m0.y + a[r].z*m0.z + a[r].w*m0.w
                 + c[r].x*m1.x + c[r].y*m1.y + c[r].z*m1.z + c[r].w*m1.w;
        }
        // Full sum of row (lane>>3)&7, on every lane.
        float x = reduce8(s);
        // Wave-parallel fast transcendental (8x redundant, one issue).
        float e = exp_tanh(x + bv);
        // Lanes 0,8,...,56 store rows 0..7 -> 8 consecutive dwords, coalesced.
        if ((lane & 7) == 0)
            out[(size_t)row0 + r0 + ((lane >> 3) & 7)] = e;
        // Sum the 8 distinct row-values: butterfly over lane bits 3..5 only.
        float y = e;
        y += __shfl_xor(y, 8, WAVE);
        y += __shfl_xor(y, 16, WAVE);
        y += __shfl_xor(y, 32, WAVE);
        wave_sum += y;
    }
    if (lane == 0)
        atomicAdd(&sums[b], wave_sum);     // 64 addresses, 128 adds each
}

// ---------------------------------------------------------------------------
// Kernel 3: out[b,t] /= sums[b]. One float4 per thread, 32768 threads.
// ---------------------------------------------------------------------------
__global__ __launch_bounds__(256, 4)
void normalize_kernel(float* __restrict__ out,
                      const float* __restrict__ sums) {
    const int idx = (int)(blockIdx.x * blockDim.x + threadIdx.x);  // f4 index
    const int b   = idx >> 9;                                      // 512 f4 / row
    const float inv = 1.f / sums[b];
    float4* p = (float4*)out + idx;
    float4 v = *p;
    v.x *= inv; v.y *= inv; v.z *= inv; v.w *= inv;
    *p = v;
}

// ---------------------------------------------------------------------------
extern "C" void kernel_launch(void* const* d_in, const int* in_sizes, int n_in,
                              void* d_out, int out_size, void* d_ws, size_t ws_size,
                              hipStream_t stream) {
    const float* query = (const float*)d_in[0];   // [B, Q]
    const float* key   = (const float*)d_in[1];   // [B, T, K]
    const float* W     = (const float*)d_in[2];   // [K, Q]
    const float* bias  = (const float*)d_in[3];   // [1]
    float* out  = (float*)d_out;                  // [B, T]
    float* mids = (float*)d_ws;                   // [B, K] scratch (128 KB)
    float* sums = mids + 64 * 512;                // [B] softmax denominators

    // 1) mids: 4096 waves (8 k-outputs each) -> 1024 blocks; also zeroes sums
    mids_kernel<<<1024, 256, 0, stream>>>(W, query, mids, sums);

    // 2) scores+exp+denominator: 8192 waves (16 rows each) -> 2048 blocks
    scores_kernel<<<2048, 256, 0, stream>>>(key, mids, bias, out, sums);

    // 3) normalize: 64*2048/4 = 32768 float4 -> 128 blocks of 256
    normalize_kernel<<<128, 256, 0, stream>>>(out, sums);
}

// Round 3
// 344.036 us; speedup vs baseline: 1.1186x; 1.1186x over previous
//
#include <hip/hip_runtime.h>
#include <math.h>

#define WAVE 64

// Native clang vector type — required for __builtin_nontemporal_load.
typedef float nfloat4 __attribute__((ext_vector_type(4)));

// Shapes fixed by reference: B=64, T=2048, Q=512, K=512.

// ---------------------------------------------------------------------------
// Fast out = exp(tanh(u)).
// tanh(u) = 1 - 2/(1 + e^{2u}); e^{2u} via v_exp_f32 (exp2), 2/(1+z) via
// v_rcp_f32. Saturates correctly: u>>0 -> z=inf -> rcp=0 -> t=1;
// u<<0 -> z=0 -> t=-1. ~8 VALU instrs vs ~100 for libm tanhf+expf.
// ---------------------------------------------------------------------------
#define LOG2E 1.44269504088896f
__device__ __forceinline__ float exp_tanh(float u) {
    float z = __builtin_amdgcn_exp2f(2.0f * LOG2E * u);   // e^{2u}
    float t = 1.0f - 2.0f * __builtin_amdgcn_rcpf(1.0f + z);
    return __builtin_amdgcn_exp2f(LOG2E * t);
}

// ---------------------------------------------------------------------------
// Reduce-scatter + broadcast: input s[0..7] = per-lane partials of 8 rows.
// Output: every lane holds the FULL 64-lane sum of row r = (lane>>3)&7.
// 10 shuffles total vs 48 for the naive 6-step-butterfly-per-row.
// ---------------------------------------------------------------------------
__device__ __forceinline__ float reduce8(const float s[8]) {
    const int lane = (int)(threadIdx.x & 63);
    const bool hi32 = (lane & 32) != 0;
    float v[4];
    #pragma unroll
    for (int r = 0; r < 4; ++r) {
        float keep = hi32 ? s[r + 4] : s[r];
        float send = hi32 ? s[r] : s[r + 4];
        v[r] = keep + __shfl_xor(send, 32, WAVE);
    }
    const bool hi16 = (lane & 16) != 0;
    float w[2];
    #pragma unroll
    for (int r = 0; r < 2; ++r) {
        float keep = hi16 ? v[r + 2] : v[r];
        float send = hi16 ? v[r] : v[r + 2];
        w[r] = keep + __shfl_xor(send, 16, WAVE);
    }
    const bool hi8 = (lane & 8) != 0;
    float keep = hi8 ? w[1] : w[0];
    float send = hi8 ? w[0] : w[1];
    float x = keep + __shfl_xor(send, 8, WAVE);
    x += __shfl_xor(x, 4, WAVE);
    x += __shfl_xor(x, 2, WAVE);
    x += __shfl_xor(x, 1, WAVE);
    return x;
}

// ---------------------------------------------------------------------------
// Kernel 1: mids[b,k] = sum_q W[k,q] * query[b,q]
// One wave per 8 consecutive k for one b. W (1 MB) is L2/L3-resident.
// ---------------------------------------------------------------------------
__global__ __launch_bounds__(256, 4)
void mids_kernel(const float* __restrict__ W,
                 const float* __restrict__ query,
                 float* __restrict__ mids) {
    const int gwave = (int)((blockIdx.x * blockDim.x + threadIdx.x) >> 6);
    const int lane  = threadIdx.x & 63;
    const int b  = gwave >> 6;          // 64 waves per batch row (512/8)
    const int k0 = (gwave & 63) * 8;

    const float4* qrow = (const float4*)(query + (size_t)b * 512);
    const float4 q0 = qrow[lane];
    const float4 q1 = qrow[lane + 64];

    float s[8];
    #pragma unroll
    for (int r = 0; r < 8; ++r) {
        const float4* wrow = (const float4*)(W + (size_t)(k0 + r) * 512);
        float4 a = wrow[lane];
        float4 c = wrow[lane + 64];
        s[r] = a.x*q0.x + a.y*q0.y + a.z*q0.z + a.w*q0.w
             + c.x*q1.x + c.y*q1.y + c.z*q1.z + c.w*q1.w;
    }
    float x = reduce8(s);
    // Lanes 0,8,...,56 hold rows 0..7 -> 8 consecutive dwords, coalesced.
    if ((lane & 7) == 0)
        mids[(size_t)gwave * 8 + ((lane >> 3) & 7)] = x;
}

// ---------------------------------------------------------------------------
// Kernel 2: out[b,t] = exp(tanh(key[b,t,:].mids[b,:] + bias)) (unnormalized)
// tanh in (-1,1) => exp cannot overflow => max-subtraction unnecessary, so
// the softmax numerator fuses here. Per-wave exp-sum is stored as a PLAIN
// per-wave partial (partial[gwave]) — NO atomics. Round 1/2's atomicAdd
// into 64 consecutive dwords (2 cache lines) serialized ~8192 memory-side
// atomics at kernel tail (~+37 us); coalesced partial stores have zero
// contention and the reduction moves to normalize_kernel.
// ---------------------------------------------------------------------------
__global__ __launch_bounds__(256, 4)
void scores_kernel(const float* __restrict__ key,
                   const float* __restrict__ mids,
                   const float* __restrict__ bias,
                   float* __restrict__ out,
                   float* __restrict__ partial) {
    const int gwave = (int)((blockIdx.x * blockDim.x + threadIdx.x) >> 6);
    const int lane  = threadIdx.x & 63;
    const int row0  = gwave * 16;          // flattened (b*T + t)
    const int b     = row0 >> 11;          // T = 2048

    const float4* mrow = (const float4*)(mids + (size_t)b * 512);
    const float4 m0 = mrow[lane];
    const float4 m1 = mrow[lane + 64];
    const float bv = bias[0];

    const nfloat4* kbase = (const nfloat4*)key + (size_t)row0 * 128;  // 128 f4/row

    float wave_sum = 0.f;

    #pragma unroll
    for (int g = 0; g < 2; ++g) {          // two 8-row groups
        const int r0 = g * 8;
        nfloat4 a[8], c[8];
        #pragma unroll
        for (int r = 0; r < 8; ++r) {
            a[r] = __builtin_nontemporal_load(&kbase[(size_t)(r0 + r) * 128 + lane]);
            c[r] = __builtin_nontemporal_load(&kbase[(size_t)(r0 + r) * 128 + lane + 64]);
        }
        float s[8];
        #pragma unroll
        for (int r = 0; r < 8; ++r) {
            s[r] = a[r].x*m0.x + a[r].y*m0.y + a[r].z*m0.z + a[r].w*m0.w
                 + c[r].x*m1.x + c[r].y*m1.y + c[r].z*m1.z + c[r].w*m1.w;
        }
        // Full sum of row (lane>>3)&7, on every lane.
        float x = reduce8(s);
        // Wave-parallel fast transcendental (8x redundant, one issue).
        float e = exp_tanh(x + bv);
        // Lanes 0,8,...,56 store rows 0..7 -> 8 consecutive dwords, coalesced.
        if ((lane & 7) == 0)
            out[(size_t)row0 + r0 + ((lane >> 3) & 7)] = e;
        // Sum the 8 distinct row-values: butterfly over lane bits 3..5 only.
        float y = e;
        y += __shfl_xor(y, 8, WAVE);
        y += __shfl_xor(y, 16, WAVE);
        y += __shfl_xor(y, 32, WAVE);
        wave_sum += y;
    }
    if (lane == 0)
        partial[gwave] = wave_sum;         // plain store, no contention
}

// ---------------------------------------------------------------------------
// Kernel 3: one block per batch row. Reduce the row's 128 wave-partials,
// then out[b,t] *= 1/sum. 64 blocks x 256 threads.
// ---------------------------------------------------------------------------
__global__ __launch_bounds__(256, 4)
void normalize_kernel(float* __restrict__ out,
                      const float* __restrict__ partial) {
    const int b   = blockIdx.x;
    const int tid = threadIdx.x;

    __shared__ float red[4];

    // 128 partials for this row live in partial[b*128 .. +128).
    float v = (tid < 128) ? partial[b * 128 + tid] : 0.f;
    #pragma unroll
    for (int off = 32; off > 0; off >>= 1)
        v += __shfl_xor(v, off, WAVE);
    if ((tid & 63) == 0) red[tid >> 6] = v;
    __syncthreads();
    const float inv = 1.f / (red[0] + red[1]);   // waves 2,3 contributed 0

    float4* row = (float4*)(out + (size_t)b * 2048);   // 512 float4
    #pragma unroll
    for (int i = 0; i < 2; ++i) {
        float4 x = row[tid + i * 256];
        x.x *= inv; x.y *= inv; x.z *= inv; x.w *= inv;
        row[tid + i * 256] = x;
    }
}

// ---------------------------------------------------------------------------
extern "C" void kernel_launch(void* const* d_in, const int* in_sizes, int n_in,
                              void* d_out, int out_size, void* d_ws, size_t ws_size,
                              hipStream_t stream) {
    const float* query = (const float*)d_in[0];   // [B, Q]
    const float* key   = (const float*)d_in[1];   // [B, T, K]
    const float* W     = (const float*)d_in[2];   // [K, Q]
    const float* bias  = (const float*)d_in[3];   // [1]
    float* out  = (float*)d_out;                  // [B, T]
    float* mids = (float*)d_ws;                   // [B, K] scratch (128 KB)
    float* partial = mids + 64 * 512;             // [8192] per-wave exp-sums

    // 1) mids: 4096 waves (8 k-outputs each) -> 1024 blocks
    mids_kernel<<<1024, 256, 0, stream>>>(W, query, mids);

    // 2) scores+exp+partial sums: 8192 waves (16 rows each) -> 2048 blocks
    scores_kernel<<<2048, 256, 0, stream>>>(key, mids, bias, out, partial);

    // 3) reduce partials + normalize: one block per batch row
    normalize_kernel<<<64, 256, 0, stream>>>(out, partial);
}